// Round 5
// baseline (110.961 us; speedup 1.0000x reference)
//
#include <hip/hip_runtime.h>
#include <math.h>

namespace {
constexpr int K = 15;
constexpr int FD = 128;
constexpr int FS = 160;
constexpr int OV = 40;
constexpr int NFRAMES = 500;
constexpr int NSAMP = NFRAMES * FS;   // 80000
constexpr float C_CONST = 0.11512925464970229f;
constexpr float LOG_GAIN_LIMIT = 10.0f * C_CONST;
constexpr float GAIN_A = 6.0f * C_CONST;
constexpr float PI_F = 3.14159265358979323846f;

constexpr int K1FPB = 15;             // params kernel: frames per block
constexpr int SFSTR = 132;            // padded feature row stride
constexpr int GPF = FS / 4;           // output float4-groups per frame = 40
}

// =====================  K1: per-frame params  =====================
// params[g][0..14] = ggain*gain*inv_norm * kern[k];  params[g][15] = ggain
__global__ __launch_bounds__(256)
void params_kernel(const float* __restrict__ feat,   // (G, FD)
                   const float* __restrict__ ck_w,   // (K, FD)
                   const float* __restrict__ ck_b,   // (K)
                   const float* __restrict__ fg_w,   // (FD)
                   const float* __restrict__ fg_b,   // (1)
                   const float* __restrict__ gg_w,   // (FD)
                   const float* __restrict__ gg_b,   // (1)
                   float* __restrict__ params,       // (G, 16)
                   int G)
{
    const int tid = threadIdx.x;
    const int g0  = blockIdx.x * K1FPB;

    __shared__ __align__(16) float sfeat[K1FPB][SFSTR];
    __shared__ float sdots[K1FPB][17];

    for (int i = tid; i < K1FPB * (FD / 4); i += 256) {
        const int fi = i >> 5;
        const int e4 = i & 31;
        const int g  = g0 + fi;
        float4 v = make_float4(0.f, 0.f, 0.f, 0.f);
        if (g < G) v = ((const float4*)feat)[(size_t)g * (FD / 4) + e4];
        *(float4*)&sfeat[fi][e4 * 4] = v;
    }
    __syncthreads();

    if (tid < K1FPB * 17) {
        const int fi = tid / 17;
        const int j  = tid - fi * 17;
        const float* wrow = (j < K) ? (ck_w + (size_t)j * FD)
                                    : ((j == K) ? fg_w : gg_w);
        const float4* w4 = (const float4*)wrow;
        const float4* f4 = (const float4*)&sfeat[fi][0];
        float4 acc = make_float4(0.f, 0.f, 0.f, 0.f);
        #pragma unroll
        for (int i = 0; i < FD / 4; ++i) {
            const float4 a = f4[i];
            const float4 w = w4[i];
            acc.x += a.x * w.x; acc.y += a.y * w.y;
            acc.z += a.z * w.z; acc.w += a.w * w.w;
        }
        const float bias = (j < K) ? ck_b[j] : ((j == K) ? fg_b[0] : gg_b[0]);
        sdots[fi][j] = acc.x + acc.y + acc.z + acc.w + bias;
    }
    __syncthreads();

    if (tid < K1FPB) {
        const int g = g0 + tid;
        if (g < G) {
            float kern[K];
            float n2 = 0.f;
            #pragma unroll
            for (int k = 0; k < K; ++k) {
                kern[k] = sdots[tid][k];
                n2 += kern[k] * kern[k];
            }
            const float inv   = 1.f / (1e-6f + sqrtf(n2));
            const float gain  = expf(-fmaxf(sdots[tid][K], 0.f) + LOG_GAIN_LIMIT);
            const float ggain = expf(GAIN_A * tanhf(sdots[tid][K + 1]));
            const float ks    = ggain * gain * inv;
            float p[16];
            #pragma unroll
            for (int k = 0; k < K; ++k) p[k] = ks * kern[k];
            p[15] = ggain;
            float4* dst = (float4*)(params + (size_t)g * 16);
            dst[0] = *(float4*)&p[0];
            dst[1] = *(float4*)&p[4];
            dst[2] = *(float4*)&p[8];
            dst[3] = *(float4*)&p[12];
        }
    }
}

// =====================  K2: synthesis (no LDS, no barriers)  =====================
// One thread per 4-output group. Direct unaligned float4 gathers from x.
__global__ __launch_bounds__(256)
void synth_kernel(const float* __restrict__ x,      // (B, NSAMP)
                  const int*   __restrict__ lags,   // (B, NF)
                  const float* __restrict__ params, // (G, 16)
                  float* __restrict__ out,          // (B, NSAMP)
                  int total)                        // B * NFRAMES * GPF
{
    const int gidx = blockIdx.x * 256 + threadIdx.x;
    if (gidx >= total) return;
    const int b  = gidx / (NFRAMES * GPF);
    const int r  = gidx - b * (NFRAMES * GPF);
    const int f  = r / GPF;
    const int gi = r - f * GPF;
    const int t  = gi * 4;

    const float* xb = x + (size_t)b * NSAMP;

    // ---- main conv window: 20 floats starting at base (unaligned float4 ok) ----
    float w[20];
    {
        const int base = f * FS - lags[b * NFRAMES + f] - 7 + t;
        if (base >= 0 && base + 19 < NSAMP) {
            #pragma unroll
            for (int q = 0; q < 5; ++q)
                *(float4*)&w[4 * q] = *(const float4*)(xb + base + 4 * q);
        } else {
            #pragma unroll
            for (int j = 0; j < 20; ++j) {
                const int idx = base + j;
                w[j] = (idx >= 0 && idx < NSAMP) ? xb[idx] : 0.f;
            }
        }
    }

    // ---- params (L1-broadcast: 40 threads share each frame's 64B) ----
    float kc[16];
    {
        const float4* pp = (const float4*)(params + ((size_t)b * NFRAMES + f) * 16);
        #pragma unroll
        for (int q = 0; q < 4; ++q) *(float4*)&kc[4 * q] = pp[q];
    }

    const float4 pt = *(const float4*)(xb + f * FS + t);   // pass-through

    float4 res;
    {
        float c0 = 0.f, c1 = 0.f, c2 = 0.f, c3 = 0.f;
        #pragma unroll
        for (int k = 0; k < K; ++k) {
            const float kk = kc[k];
            c0 += w[k]     * kk;
            c1 += w[k + 1] * kk;
            c2 += w[k + 2] * kk;
            c3 += w[k + 3] * kk;
        }
        const float ps = kc[15];
        res.x = c0 + ps * pt.x; res.y = c1 + ps * pt.y;
        res.z = c2 + ps * pt.z; res.w = c3 + ps * pt.w;
    }

    // ---- head: crossfade with previous frame's tail ----
    if (gi < OV / 4) {
        float4 w2;
        w2.x = 0.5f + 0.5f * cosf(((float)t + 0.5f) * (PI_F / OV));
        w2.y = 0.5f + 0.5f * cosf(((float)t + 1.5f) * (PI_F / OV));
        w2.z = 0.5f + 0.5f * cosf(((float)t + 2.5f) * (PI_F / OV));
        w2.w = 0.5f + 0.5f * cosf(((float)t + 3.5f) * (PI_F / OV));
        if (f > 0) {
            float wv[20];
            const int base2 = (f - 1) * FS - lags[b * NFRAMES + f - 1] - 7 + FS + t;
            if (base2 >= 0 && base2 + 19 < NSAMP) {
                #pragma unroll
                for (int q = 0; q < 5; ++q)
                    *(float4*)&wv[4 * q] = *(const float4*)(xb + base2 + 4 * q);
            } else {
                #pragma unroll
                for (int j = 0; j < 20; ++j) {
                    const int idx = base2 + j;
                    wv[j] = (idx >= 0 && idx < NSAMP) ? xb[idx] : 0.f;
                }
            }
            float qc[16];
            const float4* qq = (const float4*)(params + ((size_t)b * NFRAMES + f - 1) * 16);
            #pragma unroll
            for (int q = 0; q < 4; ++q) *(float4*)&qc[4 * q] = qq[q];

            float c0 = 0.f, c1 = 0.f, c2 = 0.f, c3 = 0.f;
            #pragma unroll
            for (int k = 0; k < K; ++k) {
                const float kk = qc[k];
                c0 += wv[k]     * kk;
                c1 += wv[k + 1] * kk;
                c2 += wv[k + 2] * kk;
                c3 += wv[k + 3] * kk;
            }
            const float ps = qc[15];
            const float4 tail = make_float4(c0 + ps * pt.x, c1 + ps * pt.y,
                                            c2 + ps * pt.z, c3 + ps * pt.w);
            res.x = res.x * (1.f - w2.x) + tail.x * w2.x;
            res.y = res.y * (1.f - w2.y) + tail.y * w2.y;
            res.z = res.z * (1.f - w2.z) + tail.z * w2.z;
            res.w = res.w * (1.f - w2.w) + tail.w * w2.w;
        } else {
            res.x *= (1.f - w2.x); res.y *= (1.f - w2.y);
            res.z *= (1.f - w2.z); res.w *= (1.f - w2.w);
        }
    }

    *(float4*)(out + (size_t)b * NSAMP + f * FS + t) = res;
}

extern "C" void kernel_launch(void* const* d_in, const int* in_sizes, int n_in,
                              void* d_out, int out_size, void* d_ws, size_t ws_size,
                              hipStream_t stream) {
    const float* x    = (const float*)d_in[0];
    const float* feat = (const float*)d_in[1];
    const int*   lags = (const int*)d_in[2];
    const float* ck_w = (const float*)d_in[3];
    const float* ck_b = (const float*)d_in[4];
    const float* fg_w = (const float*)d_in[5];
    const float* fg_b = (const float*)d_in[6];
    const float* gg_w = (const float*)d_in[7];
    const float* gg_b = (const float*)d_in[8];
    float* out    = (float*)d_out;
    float* params = (float*)d_ws;      // (B*NFRAMES, 16) floats = 1 MB

    const int B = in_sizes[0] / NSAMP;
    const int G = B * NFRAMES;

    const int nblk1 = (G + K1FPB - 1) / K1FPB;
    params_kernel<<<dim3(nblk1), dim3(256), 0, stream>>>(
        feat, ck_w, ck_b, fg_w, fg_b, gg_w, gg_b, params, G);

    const int total = G * GPF;
    const int nblk2 = (total + 255) / 256;
    synth_kernel<<<dim3(nblk2), dim3(256), 0, stream>>>(
        x, lags, params, out, total);
}

// Round 6
// 109.748 us; speedup vs baseline: 1.0111x; 1.0111x over previous
//
#include <hip/hip_runtime.h>
#include <math.h>

namespace {
constexpr int K = 15;
constexpr int FD = 128;
constexpr int FS = 160;
constexpr int OV = 40;
constexpr int NFRAMES = 500;
constexpr int NSAMP = NFRAMES * FS;   // 80000
constexpr float C_CONST = 0.11512925464970229f;
constexpr float LOG_GAIN_LIMIT = 10.0f * C_CONST;
constexpr float GAIN_A = 6.0f * C_CONST;
constexpr float PI_F = 3.14159265358979323846f;

constexpr int FPB = 6;                // frames per block (240 output threads)
constexpr int NFR = FPB + 1;          // + previous frame (overlap-add tail)
constexpr int BPB = (NFRAMES + FPB - 1) / FPB;   // 84 blocks per batch row
constexpr int SFSTR = 132;            // padded feature row stride
constexpr int GPF = FS / 4;           // 40 float4 output groups per frame
}

// Single fused kernel: params (redundant per block, cheap) + direct-gather synthesis.
__global__ __launch_bounds__(256)
void comb_fused(const float* __restrict__ x,      // (B, NSAMP)
                const float* __restrict__ feat,   // (B, NF, FD)
                const int*   __restrict__ lags,   // (B, NF)
                const float* __restrict__ ck_w,   // (K, FD)
                const float* __restrict__ ck_b,   // (K)
                const float* __restrict__ fg_w,   // (FD)
                const float* __restrict__ fg_b,   // (1)
                const float* __restrict__ gg_w,   // (FD)
                const float* __restrict__ gg_b,   // (1)
                float* __restrict__ out)          // (B, NSAMP)
{
    const int tid = threadIdx.x;
    const int bid = blockIdx.x;
    const int b   = bid / BPB;
    const int blk = bid - b * BPB;
    const int f0  = blk * FPB;

    __shared__ __align__(16) float sfeat[NFR][SFSTR];
    __shared__ float sdots[NFR][17];
    __shared__ __align__(16) float sfk[NFR][16];   // [0..14]=ks*kern, [15]=ggain

    const float* xb = x + (size_t)b * NSAMP;

    // ---- phase A: stage features for frames f0-1 .. f0+FPB-1 (one round, 224 thr) ----
    if (tid < NFR * (FD / 4)) {
        const int fr = tid >> 5;          // /32
        const int e4 = tid & 31;
        const int pf = f0 - 1 + fr;
        float4 v = make_float4(0.f, 0.f, 0.f, 0.f);
        if (pf >= 0 && pf < NFRAMES)
            v = ((const float4*)feat)[((size_t)b * NFRAMES + pf) * (FD / 4) + e4];
        *(float4*)&sfeat[fr][e4 * 4] = v;
    }
    __syncthreads();

    // ---- phase B: 17 dots per frame (119 threads) ----
    if (tid < NFR * 17) {
        const int fr = tid / 17;
        const int j  = tid - fr * 17;
        const float* wrow = (j < K) ? (ck_w + (size_t)j * FD)
                                    : ((j == K) ? fg_w : gg_w);
        const float4* w4 = (const float4*)wrow;
        const float4* f4 = (const float4*)&sfeat[fr][0];
        float4 acc = make_float4(0.f, 0.f, 0.f, 0.f);
        #pragma unroll
        for (int i = 0; i < FD / 4; ++i) {
            const float4 a = f4[i];
            const float4 w = w4[i];
            acc.x += a.x * w.x; acc.y += a.y * w.y;
            acc.z += a.z * w.z; acc.w += a.w * w.w;
        }
        const float bias = (j < K) ? ck_b[j] : ((j == K) ? fg_b[0] : gg_b[0]);
        sdots[fr][j] = acc.x + acc.y + acc.z + acc.w + bias;
    }
    __syncthreads();

    // ---- phase C: finalize params (NFR threads) ----
    if (tid < NFR) {
        const int pf = f0 - 1 + tid;
        if (pf < 0 || pf >= NFRAMES) {
            #pragma unroll
            for (int k = 0; k < 16; ++k) sfk[tid][k] = 0.f;   // zero => tail/out 0
        } else {
            float kern[K];
            float n2 = 0.f;
            #pragma unroll
            for (int k = 0; k < K; ++k) {
                kern[k] = sdots[tid][k];
                n2 += kern[k] * kern[k];
            }
            const float inv   = 1.f / (1e-6f + sqrtf(n2));
            const float gain  = expf(-fmaxf(sdots[tid][K], 0.f) + LOG_GAIN_LIMIT);
            const float ggain = expf(GAIN_A * tanhf(sdots[tid][K + 1]));
            const float ks    = ggain * gain * inv;
            #pragma unroll
            for (int k = 0; k < K; ++k) sfk[tid][k] = ks * kern[k];
            sfk[tid][15] = ggain;
        }
    }
    __syncthreads();

    // ---- phase D: direct-gather conv + crossfade + store (240 threads, 1 round) ----
    if (tid < FPB * GPF) {
        const int frl = tid / GPF;        // 0..FPB-1
        const int gi  = tid - frl * GPF;  // 0..39
        const int t   = gi * 4;
        const int f   = f0 + frl;
        if (f < NFRAMES) {
            const int fr = frl + 1;

            // main conv window: 20 floats at lag-shifted base (unaligned float4 ok)
            float w[20];
            {
                const int base = f * FS - lags[b * NFRAMES + f] - 7 + t;
                if (base >= 0 && base + 19 < NSAMP) {
                    #pragma unroll
                    for (int q = 0; q < 5; ++q)
                        *(float4*)&w[4 * q] = *(const float4*)(xb + base + 4 * q);
                } else {
                    #pragma unroll
                    for (int j = 0; j < 20; ++j) {
                        const int idx = base + j;
                        w[j] = (idx >= 0 && idx < NSAMP) ? xb[idx] : 0.f;
                    }
                }
            }

            float kc[16];
            #pragma unroll
            for (int q = 0; q < 4; ++q)
                *(float4*)&kc[4 * q] = *(const float4*)&sfk[fr][4 * q];

            const float4 pt = *(const float4*)(xb + f * FS + t);

            float4 res;
            {
                float c0 = 0.f, c1 = 0.f, c2 = 0.f, c3 = 0.f;
                #pragma unroll
                for (int k = 0; k < K; ++k) {
                    const float kk = kc[k];
                    c0 += w[k]     * kk;
                    c1 += w[k + 1] * kk;
                    c2 += w[k + 2] * kk;
                    c3 += w[k + 3] * kk;
                }
                const float ps = kc[15];
                res.x = c0 + ps * pt.x; res.y = c1 + ps * pt.y;
                res.z = c2 + ps * pt.z; res.w = c3 + ps * pt.w;
            }

            if (gi < OV / 4) {   // head: crossfade with previous frame's tail
                float4 w2;
                w2.x = 0.5f + 0.5f * cosf(((float)t + 0.5f) * (PI_F / OV));
                w2.y = 0.5f + 0.5f * cosf(((float)t + 1.5f) * (PI_F / OV));
                w2.z = 0.5f + 0.5f * cosf(((float)t + 2.5f) * (PI_F / OV));
                w2.w = 0.5f + 0.5f * cosf(((float)t + 3.5f) * (PI_F / OV));

                float4 tail = make_float4(0.f, 0.f, 0.f, 0.f);
                if (f > 0) {
                    float wv[20];
                    const int base2 = (f - 1) * FS - lags[b * NFRAMES + f - 1] - 7 + FS + t;
                    if (base2 >= 0 && base2 + 19 < NSAMP) {
                        #pragma unroll
                        for (int q = 0; q < 5; ++q)
                            *(float4*)&wv[4 * q] = *(const float4*)(xb + base2 + 4 * q);
                    } else {
                        #pragma unroll
                        for (int j = 0; j < 20; ++j) {
                            const int idx = base2 + j;
                            wv[j] = (idx >= 0 && idx < NSAMP) ? xb[idx] : 0.f;
                        }
                    }
                    float qc[16];
                    #pragma unroll
                    for (int q = 0; q < 4; ++q)
                        *(float4*)&qc[4 * q] = *(const float4*)&sfk[fr - 1][4 * q];

                    float c0 = 0.f, c1 = 0.f, c2 = 0.f, c3 = 0.f;
                    #pragma unroll
                    for (int k = 0; k < K; ++k) {
                        const float kk = qc[k];
                        c0 += wv[k]     * kk;
                        c1 += wv[k + 1] * kk;
                        c2 += wv[k + 2] * kk;
                        c3 += wv[k + 3] * kk;
                    }
                    const float ps = qc[15];
                    tail = make_float4(c0 + ps * pt.x, c1 + ps * pt.y,
                                       c2 + ps * pt.z, c3 + ps * pt.w);
                }
                res.x = res.x * (1.f - w2.x) + tail.x * w2.x;
                res.y = res.y * (1.f - w2.y) + tail.y * w2.y;
                res.z = res.z * (1.f - w2.z) + tail.z * w2.z;
                res.w = res.w * (1.f - w2.w) + tail.w * w2.w;
            }

            *(float4*)(out + (size_t)b * NSAMP + f * FS + t) = res;
        }
    }
}

extern "C" void kernel_launch(void* const* d_in, const int* in_sizes, int n_in,
                              void* d_out, int out_size, void* d_ws, size_t ws_size,
                              hipStream_t stream) {
    const float* x    = (const float*)d_in[0];
    const float* feat = (const float*)d_in[1];
    const int*   lags = (const int*)d_in[2];
    const float* ck_w = (const float*)d_in[3];
    const float* ck_b = (const float*)d_in[4];
    const float* fg_w = (const float*)d_in[5];
    const float* fg_b = (const float*)d_in[6];
    const float* gg_w = (const float*)d_in[7];
    const float* gg_b = (const float*)d_in[8];
    float* out = (float*)d_out;

    const int B = in_sizes[0] / NSAMP;
    comb_fused<<<dim3(B * BPB), dim3(256), 0, stream>>>(
        x, feat, lags, ck_w, ck_b, fg_w, fg_b, gg_w, gg_b, out);
}